// Round 6
// baseline (538.536 us; speedup 1.0000x reference)
//
#include <hip/hip_runtime.h>

typedef float f4 __attribute__((ext_vector_type(4)));

#define NV 65536       // total vectors (16*4096)
#define D 64           // embedding dim
#define K 1024         // codebook size
#define LOSS_OFF 4194304
#define IDX_OFF  4194305

// Per-code squared norms, replicating numpy fp32 pairwise-8 summation exactly.
__global__ void vq_prep(const float* __restrict__ E, float* __restrict__ eSq,
                        float* __restrict__ loss) {
  int k = blockIdx.x * 256 + threadIdx.x;
  if (k == 0) *loss = 0.0f;
  if (k < K) {
    const float* row = E + (size_t)k * D;
    float r[8];
#pragma unroll
    for (int j = 0; j < 8; ++j) r[j] = __fmul_rn(row[j], row[j]);
#pragma unroll
    for (int i = 8; i < D; i += 8)
#pragma unroll
      for (int j = 0; j < 8; ++j)
        r[j] = __fadd_rn(r[j], __fmul_rn(row[i + j], row[i + j]));
    eSq[k] = __fadd_rn(
        __fadd_rn(__fadd_rn(r[0], r[1]), __fadd_rn(r[2], r[3])),
        __fadd_rn(__fadd_rn(r[4], r[5]), __fadd_rn(r[6], r[7])));
  }
}

// ---- named-register helpers ----
#define DECL8(p) f4 p##0, p##1, p##2, p##3, p##4, p##5, p##6, p##7;
#define LD8(p, base)                                                   \
  p##0 = (base)[0]; p##1 = (base)[1]; p##2 = (base)[2];                \
  p##3 = (base)[3]; p##4 = (base)[4]; p##5 = (base)[5];                \
  p##6 = (base)[6]; p##7 = (base)[7];
#define FMA4(m, p, x)                                                  \
  m = fmaf((p)[0], (x)[0], m); m = fmaf((p)[1], (x)[1], m);            \
  m = fmaf((p)[2], (x)[2], m); m = fmaf((p)[3], (x)[3], m);
#define CH32(m, p)                                                     \
  FMA4(m, p##0, X0) FMA4(m, p##1, X1) FMA4(m, p##2, X2)                \
  FMA4(m, p##3, X3) FMA4(m, p##4, X4) FMA4(m, p##5, X5)                \
  FMA4(m, p##6, X6) FMA4(m, p##7, X7)
#define SQE(v, e) __fmul_rn((v)[e], (v)[e])
// fresh 4-term chain (numpy r_j over this lane's 4 strided elements)
#define BCH(j, A, B, C, Dq, e)                                         \
  float b##j = __fadd_rn(__fadd_rn(__fadd_rn(                          \
      SQE(A, e), SQE(B, e)), SQE(C, e)), SQE(Dq, e));
// continue lo's partial with this lane's 4 elements (valid on hi lanes)
#define RCH(j, A, B, C, Dq, e)                                         \
  float t##j = __shfl_xor(b##j, 32, 64);                               \
  float r##j = __fadd_rn(__fadd_rn(__fadd_rn(__fadd_rn(                \
      t##j, SQE(A, e)), SQE(B, e)), SQE(C, e)), SQE(Dq, e));

// Half-vector per lane: lane l holds dims 0-31 of vector l&31, lane l+32
// holds dims 32-63.  Per code: 32-FMA chain + shfl combine.  4 waves split
// K into quarters.  e half-rows loaded fresh per code (L2-hot, prefetched
// one code ahead); per-lane footprint ~115 VGPR -> no AGPR demotion.
__global__ __launch_bounds__(256, 3) void vq_main(
    const float* __restrict__ X, const float* __restrict__ E,
    const float* __restrict__ eSq, float* __restrict__ out) {
  __shared__ float redv[4][32];
  __shared__ int redi[4][32];
  __shared__ int sidx[32];

  const int t = threadIdx.x;
  const int lane = t & 63;
  const int vl = lane & 31;          // vector within block
  const int half = lane >> 5;        // 0: dims 0-31, 1: dims 32-63
  const int w = __builtin_amdgcn_readfirstlane(t >> 6);
  const int bv0 = blockIdx.x * 32;

  // This lane's half-vector: 32 floats in 8 named f4 regs.
  const f4* xp = reinterpret_cast<const f4*>(X + (size_t)(bv0 + vl) * D) + half * 8;
  f4 X0 = xp[0], X1 = xp[1], X2 = xp[2], X3 = xp[3];
  f4 X4 = xp[4], X5 = xp[5], X6 = xp[6], X7 = xp[7];

  // numpy-exact ||x||^2 across the lane pair: lo computes first-4-term
  // partials b_j; hi continues the chain sequentially, then the tree.
  BCH(0, X0, X2, X4, X6, 0) BCH(1, X0, X2, X4, X6, 1)
  BCH(2, X0, X2, X4, X6, 2) BCH(3, X0, X2, X4, X6, 3)
  BCH(4, X1, X3, X5, X7, 0) BCH(5, X1, X3, X5, X7, 1)
  BCH(6, X1, X3, X5, X7, 2) BCH(7, X1, X3, X5, X7, 3)
  RCH(0, X0, X2, X4, X6, 0) RCH(1, X0, X2, X4, X6, 1)
  RCH(2, X0, X2, X4, X6, 2) RCH(3, X0, X2, X4, X6, 3)
  RCH(4, X1, X3, X5, X7, 0) RCH(5, X1, X3, X5, X7, 1)
  RCH(6, X1, X3, X5, X7, 2) RCH(7, X1, X3, X5, X7, 3)
  const float xxh = __fadd_rn(
      __fadd_rn(__fadd_rn(r0, r1), __fadd_rn(r2, r3)),
      __fadd_rn(__fadd_rn(r4, r5), __fadd_rn(r6, r7)));
  const float xxo = __shfl_xor(xxh, 32, 64);
  const float xx = half ? xxh : xxo;

  const f4* eb = reinterpret_cast<const f4*>(E);
  const int c0 = w * (K / 4);        // this wave's code quarter
  const size_t hoff = (size_t)half * 8;

  DECL8(EA) DECL8(EB)
  { const f4* p = eb + ((size_t)c0 << 4) + hoff; LD8(EA, p) }

  float best = 3.4e38f;
  int bi = 0;

#pragma unroll 1
  for (int it = 0; it < K / 4; it += 2) {
    const int ca = c0 + it, cb = ca + 1;
    { const f4* p = eb + ((size_t)cb << 4) + hoff; LD8(EB, p) }
    const float ee0 = eSq[ca];
    float m0 = 0.0f;
    CH32(m0, EA)
    const float m0o = __shfl_xor(m0, 32, 64);
    const float m0f = __fadd_rn(m0, m0o);   // commutative: identical on both
    const float s0 = __fsub_rn(__fadd_rn(xx, ee0), 2.0f * m0f);
    if (s0 < best) { best = s0; bi = ca; }

    const int cn = (it + 2 < K / 4) ? ca + 2 : ca;  // clamp: harmless reload
    { const f4* p = eb + ((size_t)cn << 4) + hoff; LD8(EA, p) }
    const float ee1 = eSq[cb];
    float m1 = 0.0f;
    CH32(m1, EB)
    const float m1o = __shfl_xor(m1, 32, 64);
    const float m1f = __fadd_rn(m1, m1o);
    const float s1 = __fsub_rn(__fadd_rn(xx, ee1), 2.0f * m1f);
    if (s1 < best) { best = s1; bi = cb; }
  }

  if (half == 0) { redv[w][vl] = best; redi[w][vl] = bi; }
  __syncthreads();

  // Merge the 4 quarters lexicographically (quarter order == index order).
  if (t < 32) {
    float bv = redv[0][t];
    int b = redi[0][t];
#pragma unroll
    for (int q = 1; q < 4; ++q) {
      float ov = redv[q][t];
      int oi = redi[q][t];
      if (ov < bv || (ov == bv && oi < b)) { bv = ov; b = oi; }
    }
    sidx[t] = b;
  }
  __syncthreads();

  // Epilogue: 8 threads per vector gather the winning code row, write
  // quantized output, accumulate loss.
  const int v = t >> 3, seg = t & 7;
  const int code = sidx[v];
  const f4* er = eb + ((size_t)code << 4) + seg * 2;
  const f4* xr = reinterpret_cast<const f4*>(X + (size_t)(bv0 + v) * D) + seg * 2;
  f4* op = reinterpret_cast<f4*>(out + (size_t)(bv0 + v) * D) + seg * 2;
  float lsum = 0.0f;
#pragma unroll
  for (int i = 0; i < 2; ++i) {
    f4 e4 = er[i], x4 = xr[i];
    float d0 = e4[0] - x4[0], d1 = e4[1] - x4[1];
    float d2 = e4[2] - x4[2], d3 = e4[3] - x4[3];
    lsum += d0 * d0 + d1 * d1 + d2 * d2 + d3 * d3;
    op[i] = e4;
  }
  if (t < 32) out[IDX_OFF + bv0 + t] = (float)sidx[t];

#pragma unroll
  for (int off = 1; off < 64; off <<= 1) lsum += __shfl_xor(lsum, off, 64);
  if (lane == 0)
    atomicAdd(out + LOSS_OFF, lsum * (1.25f / (float)(NV * (size_t)D)));
}

extern "C" void kernel_launch(void* const* d_in, const int* in_sizes, int n_in,
                              void* d_out, int out_size, void* d_ws, size_t ws_size,
                              hipStream_t stream) {
  const float* X = (const float*)d_in[0];
  const float* E = (const float*)d_in[1];
  float* out = (float*)d_out;
  float* eSq = (float*)d_ws;  // 4 KB scratch
  vq_prep<<<4, 256, 0, stream>>>(E, eSq, out + LOSS_OFF);
  vq_main<<<NV / 32, 256, 0, stream>>>(X, E, eSq, out);
}

// Round 7
// 182.838 us; speedup vs baseline: 2.9454x; 2.9454x over previous
//
#include <hip/hip_runtime.h>

typedef float f4 __attribute__((ext_vector_type(4)));

#define NV 65536       // total vectors (16*4096)
#define D 64           // embedding dim
#define K 1024         // codebook size
#define LOSS_OFF 4194304
#define IDX_OFF  4194305

// Per-code squared norms, replicating numpy fp32 pairwise-8 summation exactly.
__global__ void vq_prep(const float* __restrict__ E, float* __restrict__ eSq,
                        float* __restrict__ loss) {
  int k = blockIdx.x * 256 + threadIdx.x;
  if (k == 0) *loss = 0.0f;
  if (k < K) {
    const float* row = E + (size_t)k * D;
    float r[8];
#pragma unroll
    for (int j = 0; j < 8; ++j) r[j] = __fmul_rn(row[j], row[j]);
#pragma unroll
    for (int i = 8; i < D; i += 8)
#pragma unroll
      for (int j = 0; j < 8; ++j)
        r[j] = __fadd_rn(r[j], __fmul_rn(row[i + j], row[i + j]));
    eSq[k] = __fadd_rn(
        __fadd_rn(__fadd_rn(r[0], r[1]), __fadd_rn(r[2], r[3])),
        __fadd_rn(__fadd_rn(r[4], r[5]), __fadd_rn(r[6], r[7])));
  }
}

// ---- named-register helpers ----
#define DECL8(p) f4 p##0, p##1, p##2, p##3, p##4, p##5, p##6, p##7;
#define LD8(p, base)                                                   \
  p##0 = (base)[0]; p##1 = (base)[1]; p##2 = (base)[2];                \
  p##3 = (base)[3]; p##4 = (base)[4]; p##5 = (base)[5];                \
  p##6 = (base)[6]; p##7 = (base)[7];
#define FMA4(m, p, x)                                                  \
  m = fmaf((p)[0], (x)[0], m); m = fmaf((p)[1], (x)[1], m);            \
  m = fmaf((p)[2], (x)[2], m); m = fmaf((p)[3], (x)[3], m);
#define CHLO(m, p)                                                     \
  FMA4(m, p##0, X0) FMA4(m, p##1, X1) FMA4(m, p##2, X2)                \
  FMA4(m, p##3, X3) FMA4(m, p##4, X4) FMA4(m, p##5, X5)                \
  FMA4(m, p##6, X6) FMA4(m, p##7, X7)
#define CHHI(m, p)                                                     \
  FMA4(m, p##0, X8)  FMA4(m, p##1, X9)  FMA4(m, p##2, X10)             \
  FMA4(m, p##3, X11) FMA4(m, p##4, X12) FMA4(m, p##5, X13)             \
  FMA4(m, p##6, X14) FMA4(m, p##7, X15)
#define SQ(v, e) __fmul_rn((v)[e], (v)[e])
#define NRM(a, b)                                                      \
  r0 = __fadd_rn(r0, SQ(a, 0)); r1 = __fadd_rn(r1, SQ(a, 1));          \
  r2 = __fadd_rn(r2, SQ(a, 2)); r3 = __fadd_rn(r3, SQ(a, 3));          \
  r4 = __fadd_rn(r4, SQ(b, 0)); r5 = __fadd_rn(r5, SQ(b, 1));          \
  r6 = __fadd_rn(r6, SQ(b, 2)); r7 = __fadd_rn(r7, SQ(b, 3));

// One vector per lane (x in 16 named f4 = 64 VGPR).  4 waves split K into
// quarters.  Codebook rows are loaded through wave-UNIFORM addresses
// (readfirstlane-pinned) -> scalar s_load -> SGPR half-buffers; the inner
// FMA is v_fmac(vdst, s, v) so e costs ZERO VGPRs.  Each 32-FMA chain
// segment covers the next half-row's scalar-load latency.
__global__ __launch_bounds__(256, 4) void vq_main(
    const float* __restrict__ X, const float* __restrict__ E,
    const float* __restrict__ eSq, float* __restrict__ out) {
  __shared__ float redv[4][64];
  __shared__ int redi[4][64];
  __shared__ int sidx[64];

  const int t = threadIdx.x;
  const int lane = t & 63;
  const int w = t >> 6;              // wave id
  const int bv0 = blockIdx.x * 64;

  // This lane's vector: 64 floats in 16 named f4 registers.
  const f4* xp = reinterpret_cast<const f4*>(X + (size_t)(bv0 + lane) * D);
  f4 X0 = xp[0], X1 = xp[1], X2 = xp[2], X3 = xp[3];
  f4 X4 = xp[4], X5 = xp[5], X6 = xp[6], X7 = xp[7];
  f4 X8 = xp[8], X9 = xp[9], X10 = xp[10], X11 = xp[11];
  f4 X12 = xp[12], X13 = xp[13], X14 = xp[14], X15 = xp[15];

  // numpy-exact ||x||^2: pairwise-8, separate mul/add rounding.
  float r0 = SQ(X0, 0), r1 = SQ(X0, 1), r2 = SQ(X0, 2), r3 = SQ(X0, 3);
  float r4 = SQ(X1, 0), r5 = SQ(X1, 1), r6 = SQ(X1, 2), r7 = SQ(X1, 3);
  NRM(X2, X3) NRM(X4, X5) NRM(X6, X7) NRM(X8, X9)
  NRM(X10, X11) NRM(X12, X13) NRM(X14, X15)
  const float xx = __fadd_rn(
      __fadd_rn(__fadd_rn(r0, r1), __fadd_rn(r2, r3)),
      __fadd_rn(__fadd_rn(r4, r5), __fadd_rn(r6, r7)));

  // This wave's code quarter, pinned uniform for scalar selection.
  const int c0 = __builtin_amdgcn_readfirstlane(w * (K / 4));

  DECL8(U) DECL8(V)   // SGPR half-buffers (dims 0-31 / 32-63)
  { const f4* p = reinterpret_cast<const f4*>(E + ((size_t)c0 << 6)); LD8(U, p) }

  float best = 3.4e38f;
  int bi = 0;

#pragma unroll 1
  for (int cc = 0; cc < K / 4; cc += 2) {
    const int ca = __builtin_amdgcn_readfirstlane(c0 + cc);
    const float* pa = E + ((size_t)ca << 6);

    // ---- code ca ----
    { const f4* p = reinterpret_cast<const f4*>(pa + 32); LD8(V, p) }  // B(ca)
    const float ee0 = eSq[ca];
    float m0 = 0.0f;
    CHLO(m0, U)                                             // covers V load
    { const f4* p = reinterpret_cast<const f4*>(pa + 64); LD8(U, p) }  // A(ca+1)
    CHHI(m0, V)                                             // covers U load
    const float s0 = __fsub_rn(__fadd_rn(xx, ee0), 2.0f * m0);
    if (s0 < best) { best = s0; bi = ca; }

    // ---- code ca+1 ----
    { const f4* p = reinterpret_cast<const f4*>(pa + 96); LD8(V, p) }  // B(ca+1)
    const float ee1 = eSq[ca + 1];
    float m1 = 0.0f;
    CHLO(m1, U)
    const int cn = __builtin_amdgcn_readfirstlane(
        (cc + 2 < K / 4) ? ca + 2 : ca);                    // clamp: harmless
    { const f4* p = reinterpret_cast<const f4*>(E + ((size_t)cn << 6));
      LD8(U, p) }                                           // A(next pair)
    CHHI(m1, V)
    const float s1 = __fsub_rn(__fadd_rn(xx, ee1), 2.0f * m1);
    if (s1 < best) { best = s1; bi = ca + 1; }
  }

  redv[w][lane] = best;
  redi[w][lane] = bi;
  __syncthreads();

  // Merge the 4 quarters lexicographically (quarter order == index order,
  // so (val, idx) lex-min == numpy first-occurrence).
  if (t < 64) {
    float bv = redv[0][t];
    int b = redi[0][t];
#pragma unroll
    for (int q = 1; q < 4; ++q) {
      float ov = redv[q][t];
      int oi = redi[q][t];
      if (ov < bv || (ov == bv && oi < b)) { bv = ov; b = oi; }
    }
    sidx[t] = b;
  }
  __syncthreads();

  // Epilogue: 4 threads per vector gather the winning code row, write
  // quantized output (coalesced), accumulate loss.
  const int vv = t >> 2, seg = t & 3;
  const int code = sidx[vv];
  const f4* er = reinterpret_cast<const f4*>(E) + ((size_t)code << 4) + seg * 4;
  const f4* xr = reinterpret_cast<const f4*>(X + (size_t)(bv0 + vv) * D) + seg * 4;
  f4* op = reinterpret_cast<f4*>(out + (size_t)(bv0 + vv) * D) + seg * 4;
  float lsum = 0.0f;
#pragma unroll
  for (int i = 0; i < 4; ++i) {
    f4 e4 = er[i], x4 = xr[i];
    float d0 = e4[0] - x4[0], d1 = e4[1] - x4[1];
    float d2 = e4[2] - x4[2], d3 = e4[3] - x4[3];
    lsum += d0 * d0 + d1 * d1 + d2 * d2 + d3 * d3;
    op[i] = e4;
  }
  if (t < 64) out[IDX_OFF + bv0 + t] = (float)sidx[t];

#pragma unroll
  for (int off = 1; off < 64; off <<= 1) lsum += __shfl_xor(lsum, off, 64);
  if (lane == 0)
    atomicAdd(out + LOSS_OFF, lsum * (1.25f / (float)(NV * (size_t)D)));
}

extern "C" void kernel_launch(void* const* d_in, const int* in_sizes, int n_in,
                              void* d_out, int out_size, void* d_ws, size_t ws_size,
                              hipStream_t stream) {
  const float* X = (const float*)d_in[0];
  const float* E = (const float*)d_in[1];
  float* out = (float*)d_out;
  float* eSq = (float*)d_ws;  // 4 KB scratch
  vq_prep<<<4, 256, 0, stream>>>(E, eSq, out + LOSS_OFF);
  vq_main<<<NV / 64, 256, 0, stream>>>(X, E, eSq, out);
}

// Round 8
// 97.586 us; speedup vs baseline: 5.5186x; 1.8736x over previous
//
#include <hip/hip_runtime.h>

typedef float f4 __attribute__((ext_vector_type(4)));
typedef __attribute__((ext_vector_type(4))) float f32x4;
typedef __attribute__((ext_vector_type(8))) short bf16x8;

#define NV 65536       // total vectors (16*4096)
#define D 64           // embedding dim
#define K 1024         // codebook size
#define BM 128         // vectors per block
#define TILE 256       // codes per LDS tile
#define MARGIN 4.0e-3f // covers 2*(2*2^-7*||x||*||e||) + fp32 slop, ||x||<=16
#define CAP 32
#define LOSS_OFF 4194304
#define IDX_OFF  4194305

__device__ __forceinline__ unsigned f2bf(float f) {  // RNE fp32->bf16 (no NaN in data)
  unsigned u = __builtin_bit_cast(unsigned, f);
  return (u + 0x7fffu + ((u >> 16) & 1u)) >> 16;
}

// Per-code squared norms, replicating numpy fp32 pairwise-8 summation exactly.
__global__ void vq_prep(const float* __restrict__ E, float* __restrict__ eSq,
                        float* __restrict__ loss) {
  int k = blockIdx.x * 256 + threadIdx.x;
  if (k == 0) *loss = 0.0f;
  if (k < K) {
    const float* row = E + (size_t)k * D;
    float r[8];
#pragma unroll
    for (int j = 0; j < 8; ++j) r[j] = __fmul_rn(row[j], row[j]);
#pragma unroll
    for (int i = 8; i < D; i += 8)
#pragma unroll
      for (int j = 0; j < 8; ++j)
        r[j] = __fadd_rn(r[j], __fmul_rn(row[i + j], row[i + j]));
    eSq[k] = __fadd_rn(
        __fadd_rn(__fadd_rn(r[0], r[1]), __fadd_rn(r[2], r[3])),
        __fadd_rn(__fadd_rn(r[4], r[5]), __fadd_rn(r[6], r[7])));
  }
}

// Stage one 256-code tile of E as bf16 into XOR-swizzled LDS (row=thread).
__device__ __forceinline__ void stage_tile(const float* __restrict__ E,
                                           unsigned short* EbfL, int tile, int t) {
  const float* src = E + ((size_t)(tile * TILE + t)) * D;
  char* dst = reinterpret_cast<char*>(EbfL) + t * 128;
  const int sw = (t & 7) << 4;
#pragma unroll
  for (int s = 0; s < 8; ++s) {
    f4 a = *reinterpret_cast<const f4*>(src + s * 8);
    f4 b = *reinterpret_cast<const f4*>(src + s * 8 + 4);
    uint4 pk;
    pk.x = f2bf(a[0]) | (f2bf(a[1]) << 16);
    pk.y = f2bf(a[2]) | (f2bf(a[3]) << 16);
    pk.z = f2bf(b[0]) | (f2bf(b[1]) << 16);
    pk.w = f2bf(b[2]) | (f2bf(b[3]) << 16);
    *reinterpret_cast<uint4*>(dst + ((s * 16) ^ sw)) = pk;
  }
}

// bf16-MFMA filter (pass1: per-vector min; pass2: candidates within margin)
// + exact fp32 rescore of candidates with the proven reference-exact chain.
__global__ __launch_bounds__(256, 2) void vq_main(
    const float* __restrict__ X, const float* __restrict__ E,
    const float* __restrict__ eSq, float* __restrict__ out) {
  __shared__ unsigned short EbfL[TILE * 64];   // swizzled [256][64] bf16, 32 KB
  __shared__ unsigned short XbfL[BM * 72];     // [128][72] bf16 padded, 18 KB
  __shared__ float eSqL[K];                    // 4 KB (exact fp32 norms)
  __shared__ float AstarL[BM];
  __shared__ unsigned cntL[BM];
  __shared__ unsigned short candL[BM * CAP];   // 8 KB
  __shared__ int sidxL[BM];

  const int t = threadIdx.x;
  const int lane = t & 63;
  const int w = t >> 6;
  const int l15 = lane & 15, l4 = lane >> 4;
  const int bv0 = blockIdx.x * BM;

  // ---- stage X tile as bf16 (RNE) into padded LDS ----
  {
    const int v = t >> 1, h = t & 1;
    const f4* src = reinterpret_cast<const f4*>(X + (size_t)(bv0 + v) * D + h * 32);
    uint4* dst = reinterpret_cast<uint4*>(
        reinterpret_cast<char*>(XbfL) + v * 144 + h * 64);
#pragma unroll
    for (int q = 0; q < 4; ++q) {
      f4 a = src[2 * q], b = src[2 * q + 1];
      uint4 pk;
      pk.x = f2bf(a[0]) | (f2bf(a[1]) << 16);
      pk.y = f2bf(a[2]) | (f2bf(a[3]) << 16);
      pk.z = f2bf(b[0]) | (f2bf(b[1]) << 16);
      pk.w = f2bf(b[2]) | (f2bf(b[3]) << 16);
      dst[q] = pk;
    }
  }
#pragma unroll
  for (int i = 0; i < 4; ++i) eSqL[t + 256 * i] = eSq[t + 256 * i];
  __syncthreads();

  // A-fragments: wave w owns vectors w*32..w*32+31 (row-tiles 2w, 2w+1).
  // mfma_f32_16x16x32_bf16: A lane(l): row=l&15, k=(l>>4)*8+j.
  bf16x8 a00, a01, a10, a11;
  {
    const char* xb = reinterpret_cast<const char*>(XbfL);
    const int v0 = w * 32 + l15, v1 = v0 + 16;
    a00 = *reinterpret_cast<const bf16x8*>(xb + v0 * 144 + l4 * 16);
    a01 = *reinterpret_cast<const bf16x8*>(xb + v0 * 144 + 64 + l4 * 16);
    a10 = *reinterpret_cast<const bf16x8*>(xb + v1 * 144 + l4 * 16);
    a11 = *reinterpret_cast<const bf16x8*>(xb + v1 * 144 + 64 + l4 * 16);
  }

  float umin[8];
#pragma unroll
  for (int i = 0; i < 8; ++i) umin[i] = 3.4e38f;

  const char* eB = reinterpret_cast<const char*>(EbfL);

  // ================= PASS 1: per-vector min of u = fl(ee - 2*m~) ==========
  for (int tile = 0; tile < 4; ++tile) {
    stage_tile(E, EbfL, tile, t);
    __syncthreads();
#pragma unroll 4
    for (int ct = 0; ct < 16; ++ct) {
      const int lc = ct * 16 + l15;
      const int rsw = (lc & 7) << 4;
      bf16x8 b0 = *reinterpret_cast<const bf16x8*>(eB + lc * 128 + ((l4 * 16) ^ rsw));
      bf16x8 b1 = *reinterpret_cast<const bf16x8*>(eB + lc * 128 + ((64 + l4 * 16) ^ rsw));
      f32x4 acc0 = {0.f, 0.f, 0.f, 0.f}, acc1 = {0.f, 0.f, 0.f, 0.f};
      acc0 = __builtin_amdgcn_mfma_f32_16x16x32_bf16(a00, b0, acc0, 0, 0, 0);
      acc0 = __builtin_amdgcn_mfma_f32_16x16x32_bf16(a01, b1, acc0, 0, 0, 0);
      acc1 = __builtin_amdgcn_mfma_f32_16x16x32_bf16(a10, b0, acc1, 0, 0, 0);
      acc1 = __builtin_amdgcn_mfma_f32_16x16x32_bf16(a11, b1, acc1, 0, 0, 0);
      const float ee = eSqL[tile * TILE + lc];
#pragma unroll
      for (int r = 0; r < 4; ++r) {
        umin[r]     = fminf(umin[r],     __fmaf_rn(-2.0f, acc0[r], ee));
        umin[4 + r] = fminf(umin[4 + r], __fmaf_rn(-2.0f, acc1[r], ee));
      }
    }
    __syncthreads();
  }
  // reduce min over the 16 columns (lanes sharing l>>4)
#pragma unroll
  for (int i = 0; i < 8; ++i)
#pragma unroll
    for (int off = 1; off < 16; off <<= 1)
      umin[i] = fminf(umin[i], __shfl_xor(umin[i], off, 64));
  if (l15 == 0) {
#pragma unroll
    for (int rt = 0; rt < 2; ++rt)
#pragma unroll
      for (int r = 0; r < 4; ++r)
        AstarL[w * 32 + rt * 16 + l4 * 4 + r] = umin[rt * 4 + r];
  }
  if (t < BM) cntL[t] = 0;
  __syncthreads();

  float thr[8];
#pragma unroll
  for (int rt = 0; rt < 2; ++rt)
#pragma unroll
    for (int r = 0; r < 4; ++r)
      thr[rt * 4 + r] = AstarL[w * 32 + rt * 16 + l4 * 4 + r] + MARGIN;

  // ================= PASS 2: collect candidates (u <= A* + M) =============
  for (int tile = 0; tile < 4; ++tile) {
    stage_tile(E, EbfL, tile, t);
    __syncthreads();
#pragma unroll 4
    for (int ct = 0; ct < 16; ++ct) {
      const int lc = ct * 16 + l15;
      const int rsw = (lc & 7) << 4;
      bf16x8 b0 = *reinterpret_cast<const bf16x8*>(eB + lc * 128 + ((l4 * 16) ^ rsw));
      bf16x8 b1 = *reinterpret_cast<const bf16x8*>(eB + lc * 128 + ((64 + l4 * 16) ^ rsw));
      f32x4 acc0 = {0.f, 0.f, 0.f, 0.f}, acc1 = {0.f, 0.f, 0.f, 0.f};
      acc0 = __builtin_amdgcn_mfma_f32_16x16x32_bf16(a00, b0, acc0, 0, 0, 0);
      acc0 = __builtin_amdgcn_mfma_f32_16x16x32_bf16(a01, b1, acc0, 0, 0, 0);
      acc1 = __builtin_amdgcn_mfma_f32_16x16x32_bf16(a10, b0, acc1, 0, 0, 0);
      acc1 = __builtin_amdgcn_mfma_f32_16x16x32_bf16(a11, b1, acc1, 0, 0, 0);
      const int cg = tile * TILE + lc;
      const float ee = eSqL[cg];
#pragma unroll
      for (int r = 0; r < 4; ++r) {
        if (__fmaf_rn(-2.0f, acc0[r], ee) <= thr[r]) {
          int v = w * 32 + l4 * 4 + r;
          unsigned pos = atomicAdd(&cntL[v], 1u);
          if (pos < CAP) candL[v * CAP + pos] = (unsigned short)cg;
        }
        if (__fmaf_rn(-2.0f, acc1[r], ee) <= thr[4 + r]) {
          int v = w * 32 + 16 + l4 * 4 + r;
          unsigned pos = atomicAdd(&cntL[v], 1u);
          if (pos < CAP) candL[v * CAP + pos] = (unsigned short)cg;
        }
      }
    }
    __syncthreads();
  }

  // ====== exact fp32 rescore (bit-identical chain to passing rounds) ======
  {
    const int v = t >> 1, par = t & 1;
    const int gv = bv0 + v;
    const float* xr = X + (size_t)gv * D;
    float rr[8];
#pragma unroll
    for (int j = 0; j < 8; ++j) rr[j] = __fmul_rn(xr[j], xr[j]);
#pragma unroll
    for (int i = 8; i < 64; i += 8)
#pragma unroll
      for (int j = 0; j < 8; ++j)
        rr[j] = __fadd_rn(rr[j], __fmul_rn(xr[i + j], xr[i + j]));
    const float xx = __fadd_rn(
        __fadd_rn(__fadd_rn(rr[0], rr[1]), __fadd_rn(rr[2], rr[3])),
        __fadd_rn(__fadd_rn(rr[4], rr[5]), __fadd_rn(rr[6], rr[7])));

    float best = 3.4e38f;
    int bi = 0x7fffffff;
    const unsigned n = cntL[v];
    if (n <= CAP) {
      for (unsigned i = par; i < n; i += 2) {
        const int c = candL[v * CAP + i];
        const float* er = E + (size_t)c * D;
        float m = 0.f;
#pragma unroll
        for (int j = 0; j < 64; ++j) m = fmaf(er[j], xr[j], m);
        const float dd = __fsub_rn(__fadd_rn(xx, eSqL[c]), 2.0f * m);
        if (dd < best || (dd == best && c < bi)) { best = dd; bi = c; }
      }
    } else {  // overflow fallback: exact full scan (deterministic, correct)
      for (int c = par; c < K; c += 2) {
        const float* er = E + (size_t)c * D;
        float m = 0.f;
#pragma unroll
        for (int j = 0; j < 64; ++j) m = fmaf(er[j], xr[j], m);
        const float dd = __fsub_rn(__fadd_rn(xx, eSqL[c]), 2.0f * m);
        if (dd < best || (dd == best && c < bi)) { best = dd; bi = c; }
      }
    }
    const float ov = __shfl_xor(best, 1, 64);
    const int oi = __shfl_xor(bi, 1, 64);
    if (ov < best || (ov == best && oi < bi)) { best = ov; bi = oi; }
    if (par == 0) sidxL[v] = bi;
  }
  __syncthreads();

  // ============== epilogue: quantized out, indices, loss ==================
  {
    const int v = t >> 1, h = t & 1;
    const int gv = bv0 + v;
    const int code = sidxL[v];
    const f4* er = reinterpret_cast<const f4*>(E + (size_t)code * D + h * 32);
    const f4* xr = reinterpret_cast<const f4*>(X + (size_t)gv * D + h * 32);
    f4* op = reinterpret_cast<f4*>(out + (size_t)gv * D + h * 32);
    float lsum = 0.f;
#pragma unroll
    for (int i = 0; i < 8; ++i) {
      f4 e4 = er[i], x4 = xr[i];
      float d0 = e4[0] - x4[0], d1 = e4[1] - x4[1];
      float d2 = e4[2] - x4[2], d3 = e4[3] - x4[3];
      lsum += d0 * d0 + d1 * d1 + d2 * d2 + d3 * d3;
      op[i] = e4;
    }
    if (t < BM) out[IDX_OFF + bv0 + t] = (float)sidxL[t];
#pragma unroll
    for (int off = 1; off < 64; off <<= 1) lsum += __shfl_xor(lsum, off, 64);
    if (lane == 0)
      atomicAdd(out + LOSS_OFF, lsum * (1.25f / (float)(NV * (size_t)D)));
  }
}

extern "C" void kernel_launch(void* const* d_in, const int* in_sizes, int n_in,
                              void* d_out, int out_size, void* d_ws, size_t ws_size,
                              hipStream_t stream) {
  const float* X = (const float*)d_in[0];
  const float* E = (const float*)d_in[1];
  float* out = (float*)d_out;
  float* eSq = (float*)d_ws;  // 4 KB scratch
  vq_prep<<<4, 256, 0, stream>>>(E, eSq, out + LOSS_OFF);
  vq_main<<<NV / BM, 256, 0, stream>>>(X, E, eSq, out);
}